// Round 6
// baseline (21651.489 us; speedup 1.0000x reference)
//
#include <hip/hip_runtime.h>
#include <math.h>

#define HD 64
#define DATT 16
#define NCIN 3
#define NCOUT 2
#define HH 24
#define WW 48
#define SS (HH*WW)          // 1152
#define NB 16
#define TSTEPS 37
#define INPUT_FRAMES 12

#define PR 26
#define PC 52
#define PHW (PR*PC)         // 1352

// ---------------- workspace layout (floats) ----------------
#define OFF_H     0                      // 16*64*1352 = 1384448 (padded)
#define OFF_C     1384448                // 16*64*1152 (unpadded)
#define OFF_M     2564096                // 16*64*1152 (unpadded)
#define OFF_FEED  3743744                // 16*3*1352 (padded)
#define OFF_Z     3808640                // 16*16*1352 (padded)
#define ZERO_END  4154752                // everything above zeroed each launch
#define OFF_COMB  4154752                // 16*256*1152 = 4718592
#define OFF_QKV   4154752                // aliases comb (dead after lstm gates)
#define OFF_MKV   5039488                // qkv + 884736
#define OFF_IOG   8873344                // comb + 4718592
#define OFF_W2G   12412288               // 32*72*9*8 = 165888
#define OFF_W3G   12578176               // 24*80*9*8 = 138240
// end = 12716416 floats = 50.9 MB

__device__ __forceinline__ float sigmoidf_(float x) {
    return 1.0f / (1.0f + __expf(-x));
}

__global__ void k_zero(float* __restrict__ p, int n4) {
    int i = blockIdx.x * blockDim.x + threadIdx.x;
    if (i < n4) ((float4*)p)[i] = make_float4(0.f, 0.f, 0.f, 0.f);
}

// ---------------- weight reorder: conv_w -> w2g [ocg(32)][c(72)][kt(9)][ocl(8)] ----------------
__global__ void k_prep_w2g(const float* __restrict__ cw, float* __restrict__ w2g) {
    int idx = blockIdx.x * blockDim.x + threadIdx.x;
    if (idx >= 165888) return;
    int ocl = idx & 7;
    int kt  = (idx >> 3) % 9;
    int c   = (idx / 72) % 72;
    int ocg = idx / 5184;
    w2g[idx] = (c < 67) ? cw[(ocg * 8 + ocl) * 603 + c * 9 + kt] : 0.f;
}

// ---------------- weight reorder: o_w -> w3g [ocg(24)][c(80)][kt(9)][ocl(8)] ----------------
__global__ void k_prep_w3g(const float* __restrict__ ow, float* __restrict__ w3g) {
    int idx = blockIdx.x * blockDim.x + threadIdx.x;
    if (idx >= 138240) return;
    int ocl = idx & 7;
    int kt  = (idx >> 3) % 9;
    int c   = (idx / 72) % 80;
    int ocg = idx / 5760;
    w3g[idx] = ow[(ocg * 8 + ocl) * 720 + c * 9 + kt];
}

// ---------------- feed selection ----------------
__global__ void k_feed(const float* __restrict__ x, const float* __restrict__ outbuf,
                       float* __restrict__ feed, int t) {
    int i = blockIdx.x * blockDim.x + threadIdx.x;
    if (i >= NB * 3 * SS) return;
    int s = i % SS;
    int ch = (i / SS) % 3;
    int n = i / (3 * SS);
    int y = s / WW, xx = s % WW;
    float v;
    if (t < INPUT_FRAMES || ch == 2) {
        v = x[(((n * TSTEPS + t) * HH + y) * WW + xx) * NCIN + ch];
    } else {
        v = outbuf[(((n * TSTEPS + (t - 1)) * NCOUT + ch) * HH + y) * WW + xx];
    }
    feed[((size_t)(n * 3 + ch) * PR + (y + 1)) * PC + (xx + 1)] = v;
}

// ---------------- generic 3x3 conv, pad=1, fp32, padded inputs (r5-verbatim) ----------------
__global__ __launch_bounds__(192) void k_conv3x3(
    const float* __restrict__ in1, int C1,
    const float* __restrict__ in2, int C2,
    const float* __restrict__ w, const float* __restrict__ b,
    float* __restrict__ out, int OC)
{
    __shared__ __align__(16) float lds_patch[8 * 520];

    const int bx = blockIdx.x;
    const int n = bx / 3, tile = bx % 3;
    const int ocg = blockIdx.y;
    const int C = C1 + C2;
    const int nchunk = (C + 7) / 8;
    const int tid = threadIdx.x;
    const int y0 = tile * 8;

    const float* wg = w + (size_t)ocg * (size_t)(nchunk * 8 * 72);

    const float4* in1_4 = (const float4*)(in1 + (size_t)n * C1 * PHW);
    const float4* in2_4 = (const float4*)(in2 + (size_t)n * C2 * PHW);

    float4 pf[6];
    auto load_chunk = [&](int chunk) {
#pragma unroll
        for (int k = 0; k < 6; ++k) {
            int i = tid + 192 * k;
            if (i < 1040) {
                int c_l = i / 130;
                int rem = i - c_l * 130;
                int c = chunk * 8 + c_l;
                float4 v = make_float4(0.f, 0.f, 0.f, 0.f);
                if (c < C) {
                    v = (c < C1) ? in1_4[(c * PR + y0) * 13 + rem]
                                 : in2_4[((c - C1) * PR + y0) * 13 + rem];
                }
                pf[k] = v;
            }
        }
    };

    const int cg = tid % 24;
    const int ty = tid / 24;
    const int x0 = cg * 2;
    const int y_out = y0 + ty;

    float acc[16];
#pragma unroll
    for (int j = 0; j < 16; ++j) acc[j] = 0.f;

    load_chunk(0);
    for (int chunk = 0; chunk < nchunk; ++chunk) {
        __syncthreads();
#pragma unroll
        for (int k = 0; k < 6; ++k) {
            int i = tid + 192 * k;
            if (i < 1040) ((float4*)lds_patch)[i] = pf[k];
        }
        if (chunk + 1 < nchunk) load_chunk(chunk + 1);
        __syncthreads();

#pragma unroll 2
        for (int icl = 0; icl < 8; ++icl) {
            const int c = chunk * 8 + icl;
            const float* wb_ = wg + c * 72;
            const float* pr = &lds_patch[icl * 520 + ty * PC + x0];
#pragma unroll
            for (int ky = 0; ky < 3; ++ky) {
                const float* r = pr + ky * PC;
                float i0 = r[0], i1 = r[1], i2 = r[2], i3 = r[3];
                const float* wk = wb_ + ky * 24;
#pragma unroll
                for (int kx = 0; kx < 3; ++kx) {
                    float va = (kx == 0) ? i0 : ((kx == 1) ? i1 : i2);
                    float vb = (kx == 0) ? i1 : ((kx == 1) ? i2 : i3);
                    const float4 wa  = *(const float4*)(wk + kx * 8);
                    const float4 wb4 = *(const float4*)(wk + kx * 8 + 4);
                    acc[0]  += va * wa.x;  acc[1]  += va * wa.y;
                    acc[2]  += va * wa.z;  acc[3]  += va * wa.w;
                    acc[4]  += va * wb4.x; acc[5]  += va * wb4.y;
                    acc[6]  += va * wb4.z; acc[7]  += va * wb4.w;
                    acc[8]  += vb * wa.x;  acc[9]  += vb * wa.y;
                    acc[10] += vb * wa.z;  acc[11] += vb * wa.w;
                    acc[12] += vb * wb4.x; acc[13] += vb * wb4.y;
                    acc[14] += vb * wb4.z; acc[15] += vb * wb4.w;
                }
            }
        }
    }

#pragma unroll
    for (int j = 0; j < 8; ++j) {
        int oc = ocg * 8 + j;
        float bv = b[oc];
        float2 o2 = make_float2(acc[j] + bv, acc[8 + j] + bv);
        *(float2*)&out[((n * OC + oc) * HH + y_out) * WW + x0] = o2;
    }
}

// ---------------- ConvLSTM gates (h written padded) ----------------
__global__ void k_lstm_gates(const float* __restrict__ comb, float* __restrict__ c,
                             float* __restrict__ h) {
    int i = blockIdx.x * blockDim.x + threadIdx.x;
    if (i >= NB * HD * SS) return;
    int s = i % SS;
    int ch = (i / SS) % HD;
    int n = i / (HD * SS);
    const float* cb = comb + (size_t)n * 4 * HD * SS;
    float ci = cb[(ch) * SS + s];
    float cf = cb[(ch + HD) * SS + s];
    float co = cb[(ch + 2 * HD) * SS + s];
    float cg = cb[(ch + 3 * HD) * SS + s];
    float ig = sigmoidf_(ci);
    float fg = sigmoidf_(cf);
    float og = sigmoidf_(co);
    float gg = tanhf(cg);
    float cn = fg * c[i] + ig * gg;
    c[i] = cn;
    int y = s / WW, x = s % WW;
    h[((size_t)(n * HD + ch) * PR + (y + 1)) * PC + (x + 1)] = og * tanhf(cn);
}

// ---------------- 1x1 projections, 5 groups x 16 channels ----------------
// grid (72, 5): g=0,1,2 -> q,k,v from h ; g=3,4 -> mk,mv from m
__global__ __launch_bounds__(256) void k_qkv(
    const float* __restrict__ h, const float* __restrict__ m,
    const float* __restrict__ hw, const float* __restrict__ hb,
    const float* __restrict__ mw, const float* __restrict__ mb,
    float* __restrict__ qkv, float* __restrict__ mkv) {
    __shared__ float lw[1024];
    __shared__ float lb[16];
    const int g = blockIdx.y;
    const int tid = threadIdx.x;
    const float* wsrc = (g < 3) ? (hw + g * 1024) : (mw + (g - 3) * 1024);
    const float* bsrc = (g < 3) ? (hb + g * 16) : (mb + (g - 3) * 16);
    for (int i = tid; i < 1024; i += 256) lw[i] = wsrc[i];
    if (tid < 16) lb[tid] = bsrc[tid];
    __syncthreads();

    int idx = blockIdx.x * 256 + tid;
    int s = idx % SS;
    int n = idx / SS;
    int y = s / WW, x = s % WW;

    float reg[HD];
    if (g < 3) {
        const float* src = h + (size_t)n * HD * PHW + (y + 1) * PC + (x + 1);
#pragma unroll
        for (int ic = 0; ic < HD; ++ic) reg[ic] = src[ic * PHW];
    } else {
        const float* src = m + (size_t)n * HD * SS + s;
#pragma unroll
        for (int ic = 0; ic < HD; ++ic) reg[ic] = src[ic * SS];
    }

    float outv[16];
#pragma unroll
    for (int j = 0; j < 16; ++j) {
        const float* wr = &lw[j * HD];
        float a = lb[j];
#pragma unroll
        for (int ic = 0; ic < HD; ++ic) a += reg[ic] * wr[ic];
        outv[j] = a;
    }
    float* dst = (g < 3) ? &qkv[((size_t)n * SS + s) * 48 + g * 16]
                         : &mkv[((size_t)n * SS + s) * 32 + (g - 3) * 16];
#pragma unroll
    for (int j = 0; j < 4; ++j)
        ((float4*)dst)[j] = make_float4(outv[4*j], outv[4*j+1], outv[4*j+2], outv[4*j+3]);
}

#define LOAD16(dst, srcp) do {                       \
    float4 _a = ((const float4*)(srcp))[0];          \
    float4 _b = ((const float4*)(srcp))[1];          \
    float4 _c = ((const float4*)(srcp))[2];          \
    float4 _d = ((const float4*)(srcp))[3];          \
    dst[0]=_a.x; dst[1]=_a.y; dst[2]=_a.z; dst[3]=_a.w;   \
    dst[4]=_b.x; dst[5]=_b.y; dst[6]=_b.z; dst[7]=_b.w;   \
    dst[8]=_c.x; dst[9]=_c.y; dst[10]=_c.z; dst[11]=_c.w; \
    dst[12]=_d.x; dst[13]=_d.y; dst[14]=_d.z; dst[15]=_d.w; } while(0)

// ---------------- dual spatial attention + z 1x1, 4 rows/thread ----------------
// block 128 = 8 row-threads (4 rows each) x 16 t-partials; grid (36, 16)
// KV tile: 144 t x 68 floats (padded: 64 data + 4) -> partials hit distinct banks.
// No max-subtraction (|scores| bounded); partial merge via shfl_xor butterfly.
#define TSTRIDE 68
__global__ __launch_bounds__(128) void k_attn(
    const float* __restrict__ qkv, const float* __restrict__ mkv,
    const float* __restrict__ zw, const float* __restrict__ zb,
    float* __restrict__ Z)
{
    __shared__ __align__(16) float smem[144 * TSTRIDE];  // 39.2 KB
    const int n = blockIdx.y;
    const int tid = threadIdx.x;
    const int rowthr = tid >> 4;    // 0..7
    const int part = tid & 15;      // 0..15
    const int s0 = blockIdx.x * 32 + rowthr * 4;

    float q[4][16];
#pragma unroll
    for (int r = 0; r < 4; ++r)
        LOAD16(q[r], &qkv[((size_t)n * SS + s0 + r) * 48]);

    float lh[4] = {0.f, 0.f, 0.f, 0.f}, lm[4] = {0.f, 0.f, 0.f, 0.f};
    float oh[4][16], om[4][16];
#pragma unroll
    for (int r = 0; r < 4; ++r)
#pragma unroll
        for (int j = 0; j < 16; ++j) { oh[r][j] = 0.f; om[r][j] = 0.f; }

    const float4* qkv4 = (const float4*)qkv + (size_t)n * SS * 12;
    const float4* mkv4 = (const float4*)mkv + (size_t)n * SS * 8;

    for (int tile = 0; tile < 8; ++tile) {
        __syncthreads();
        // stage 144 t: [t][hk16|hv16|mk16|mv16] at stride 68 floats
#pragma unroll
        for (int k = 0; k < 18; ++k) {
            int j = tid + 128 * k;
            int t_loc = j >> 4, f = j & 15;
            int t = tile * 144 + t_loc;
            float4 v;
            if (f < 8) v = qkv4[t * 12 + 4 + f];
            else       v = mkv4[t * 8 + (f - 8)];
            *(float4*)&smem[t_loc * TSTRIDE + f * 4] = v;
        }
        __syncthreads();

        const int t0 = part * 9;
        for (int tl = t0; tl < t0 + 9; ++tl) {
            const float* kvb = &smem[tl * TSTRIDE];
            float kk[16], vv[16];
            // h attention
            LOAD16(kk, kvb);
            float d[4] = {0.f, 0.f, 0.f, 0.f};
#pragma unroll
            for (int j = 0; j < 16; ++j) {
#pragma unroll
                for (int r = 0; r < 4; ++r) d[r] += q[r][j] * kk[j];
            }
            float e[4];
#pragma unroll
            for (int r = 0; r < 4; ++r) { e[r] = __expf(d[r] * 0.25f); lh[r] += e[r]; }
            LOAD16(vv, kvb + 16);
#pragma unroll
            for (int j = 0; j < 16; ++j) {
#pragma unroll
                for (int r = 0; r < 4; ++r) oh[r][j] += e[r] * vv[j];
            }
            // m attention
            LOAD16(kk, kvb + 32);
            float d2[4] = {0.f, 0.f, 0.f, 0.f};
#pragma unroll
            for (int j = 0; j < 16; ++j) {
#pragma unroll
                for (int r = 0; r < 4; ++r) d2[r] += q[r][j] * kk[j];
            }
            float e2[4];
#pragma unroll
            for (int r = 0; r < 4; ++r) { e2[r] = __expf(d2[r] * 0.25f); lm[r] += e2[r]; }
            LOAD16(vv, kvb + 48);
#pragma unroll
            for (int j = 0; j < 16; ++j) {
#pragma unroll
                for (int r = 0; r < 4; ++r) om[r][j] += e2[r] * vv[j];
            }
        }
    }

    // butterfly merge across the 16 partials (lanes differing in bits 0..3)
#pragma unroll
    for (int mask = 1; mask <= 8; mask <<= 1) {
#pragma unroll
        for (int r = 0; r < 4; ++r) {
            lh[r] += __shfl_xor(lh[r], mask, 16);
            lm[r] += __shfl_xor(lm[r], mask, 16);
#pragma unroll
            for (int j = 0; j < 16; ++j) {
                oh[r][j] += __shfl_xor(oh[r][j], mask, 16);
                om[r][j] += __shfl_xor(om[r][j], mask, 16);
            }
        }
    }

    // z projection: this thread's partial id = its z-channel (16 partials = 16 z-ch)
    const int zc = part;
    const float* zr = &zw[zc * 32];
    float zrh[16], zrm[16];
    LOAD16(zrh, zr);
    LOAD16(zrm, zr + 16);
    float zbv = zb[zc];
#pragma unroll
    for (int r = 0; r < 4; ++r) {
        int s = s0 + r;
        float ilh = 1.f / lh[r];
        float ilm = 1.f / lm[r];
        float a = zbv;
#pragma unroll
        for (int j = 0; j < 16; ++j)
            a += zrh[j] * (oh[r][j] * ilh) + zrm[j] * (om[r][j] * ilm);
        int y = s / WW, x = s % WW;
        Z[((size_t)(n * DATT + zc) * PR + y + 1) * PC + x + 1] = a;
    }
}

// ---------------- SA memory gates (h written padded) ----------------
__global__ void k_sa_gates(const float* __restrict__ iog, float* __restrict__ m,
                           float* __restrict__ h) {
    int i = blockIdx.x * blockDim.x + threadIdx.x;
    if (i >= NB * HD * SS) return;
    int s = i % SS;
    int ch = (i / SS) % HD;
    int n = i / (HD * SS);
    const float* ib = iog + (size_t)n * 3 * HD * SS;
    float si = ib[ch * SS + s];
    float sg = ib[(HD + ch) * SS + s];
    float so = ib[(2 * HD + ch) * SS + s];
    si = sigmoidf_(si);
    sg = tanhf(sg);
    float mn = si * sg + (1.f - si) * m[i];
    m[i] = mn;
    int y = s / WW, x = s % WW;
    h[((size_t)(n * HD + ch) * PR + (y + 1)) * PC + (x + 1)] = sigmoidf_(so) * mn;
}

// ---------------- out 1x1 conv (64 -> 2) ----------------
__global__ void k_out(const float* __restrict__ h, const float* __restrict__ ow,
                      const float* __restrict__ ob, float* __restrict__ outbuf, int t) {
    int idx = blockIdx.x * blockDim.x + threadIdx.x;
    if (idx >= NB * SS) return;
    int s = idx % SS;
    int n = idx / SS;
    int y = s / WW, x = s % WW;
    float reg[HD];
    const float* src = h + (size_t)n * HD * PHW + (y + 1) * PC + (x + 1);
#pragma unroll
    for (int ic = 0; ic < HD; ++ic) reg[ic] = src[ic * PHW];
#pragma unroll
    for (int cc = 0; cc < NCOUT; ++cc) {
        const float* wr = &ow[cc * HD];
        float a = ob[cc];
#pragma unroll
        for (int ic = 0; ic < HD; ++ic) a += reg[ic] * wr[ic];
        outbuf[(((size_t)n * TSTEPS + t) * NCOUT + cc) * SS + s] = a;
    }
}

// ---------------- nino prediction ----------------
__global__ void k_nino(const float* __restrict__ outbuf, float* __restrict__ pred) {
    int tidx = threadIdx.x;
    if (tidx >= 16 * 24) return;
    int j = tidx % 24;
    int n = tidx / 24;
    float acc = 0.f;
    for (int f = j; f < j + 3; ++f) {
        int t = 11 + f;
        const float* p = &outbuf[(((size_t)n * TSTEPS + t) * NCOUT + 0) * SS];
        float sloc = 0.f;
        for (int y = 10; y <= 12; ++y)
            for (int x = 19; x <= 29; ++x)
                sloc += p[y * WW + x];
        acc += sloc * (1.f / 33.f);
    }
    pred[n * 24 + j] = acc * (1.f / 3.f);
}

extern "C" void kernel_launch(void* const* d_in, const int* in_sizes, int n_in,
                              void* d_out, int out_size, void* d_ws, size_t ws_size,
                              hipStream_t stream) {
    const float* x      = (const float*)d_in[0];
    const float* conv_w = (const float*)d_in[1];
    const float* conv_b = (const float*)d_in[2];
    const float* h_w    = (const float*)d_in[3];
    const float* h_b    = (const float*)d_in[4];
    const float* m_w    = (const float*)d_in[5];
    const float* m_b    = (const float*)d_in[6];
    const float* z_w    = (const float*)d_in[7];
    const float* z_b    = (const float*)d_in[8];
    const float* o_w    = (const float*)d_in[9];
    const float* o_b    = (const float*)d_in[10];
    const float* out_w  = (const float*)d_in[11];
    const float* out_b  = (const float*)d_in[12];

    float* ws   = (float*)d_ws;
    float* h    = ws + OFF_H;
    float* c    = ws + OFF_C;
    float* m    = ws + OFF_M;
    float* feed = ws + OFF_FEED;
    float* comb = ws + OFF_COMB;
    float* qkv  = ws + OFF_QKV;
    float* mkv  = ws + OFF_MKV;
    float* Zb   = ws + OFF_Z;
    float* iog  = ws + OFF_IOG;
    float* w2g  = ws + OFF_W2G;
    float* w3g  = ws + OFF_W3G;
    float* outp = (float*)d_out;

    k_zero<<<4058, 256, 0, stream>>>(ws, 1038688);
    k_prep_w2g<<<648, 256, 0, stream>>>(conv_w, w2g);
    k_prep_w3g<<<540, 256, 0, stream>>>(o_w, w3g);

    for (int t = 0; t < TSTEPS; ++t) {
        k_feed<<<216, 256, 0, stream>>>(x, outp, feed, t);
        k_conv3x3<<<dim3(48, 32), 192, 0, stream>>>(feed, 3, h, HD, w2g, conv_b,
                                                    comb, 4 * HD);
        k_lstm_gates<<<4608, 256, 0, stream>>>(comb, c, h);
        k_qkv<<<dim3(72, 5), 256, 0, stream>>>(h, m, h_w, h_b, m_w, m_b, qkv, mkv);
        k_attn<<<dim3(36, 16), 128, 0, stream>>>(qkv, mkv, z_w, z_b, Zb);
        k_conv3x3<<<dim3(48, 24), 192, 0, stream>>>(Zb, DATT, h, HD, w3g, o_b,
                                                    iog, 3 * HD);
        k_sa_gates<<<4608, 256, 0, stream>>>(iog, m, h);
        k_out<<<72, 256, 0, stream>>>(h, out_w, out_b, outp, t);
    }
    k_nino<<<1, 384, 0, stream>>>(outp, outp + (size_t)NB * TSTEPS * NCOUT * SS);
}

// Round 7
// 16588.588 us; speedup vs baseline: 1.3052x; 1.3052x over previous
//
#include <hip/hip_runtime.h>
#include <math.h>

#define HD 64
#define DATT 16
#define NCIN 3
#define NCOUT 2
#define HH 24
#define WW 48
#define SS (HH*WW)          // 1152
#define NB 16
#define TSTEPS 37
#define INPUT_FRAMES 12

#define PR 26
#define PC 52
#define PHW (PR*PC)         // 1352

// ---------------- workspace layout (floats) ----------------
#define OFF_H     0                      // 16*64*1352 = 1384448 (padded)
#define OFF_C     1384448                // 16*64*1152 (unpadded)
#define OFF_M     2564096                // 16*64*1152 (unpadded)
#define OFF_FEED  3743744                // 16*3*1352 (padded)
#define OFF_Z     3808640                // 16*16*1352 (padded)
#define ZERO_END  4154752                // everything above zeroed each launch
#define OFF_COMB  4154752                // 16*256*1152 = 4718592
#define OFF_QKV   4154752                // aliases comb (dead after lstm gates)
#define OFF_MKV   5039488                // qkv + 884736
#define OFF_IOG   8873344                // comb + 4718592
#define OFF_W2G   12412288               // 32*72*9*8 = 165888
#define OFF_W3G   12578176               // 24*80*9*8 = 138240
// end = 12716416 floats = 50.9 MB

__device__ __forceinline__ float sigmoidf_(float x) {
    return 1.0f / (1.0f + __expf(-x));
}

__global__ void k_zero(float* __restrict__ p, int n4) {
    int i = blockIdx.x * blockDim.x + threadIdx.x;
    if (i < n4) ((float4*)p)[i] = make_float4(0.f, 0.f, 0.f, 0.f);
}

// ---------------- weight reorder: conv_w -> w2g [ocg(32)][c(72)][kt(9)][ocl(8)] ----------------
__global__ void k_prep_w2g(const float* __restrict__ cw, float* __restrict__ w2g) {
    int idx = blockIdx.x * blockDim.x + threadIdx.x;
    if (idx >= 165888) return;
    int ocl = idx & 7;
    int kt  = (idx >> 3) % 9;
    int c   = (idx / 72) % 72;
    int ocg = idx / 5184;
    w2g[idx] = (c < 67) ? cw[(ocg * 8 + ocl) * 603 + c * 9 + kt] : 0.f;
}

// ---------------- weight reorder: o_w -> w3g [ocg(24)][c(80)][kt(9)][ocl(8)] ----------------
__global__ void k_prep_w3g(const float* __restrict__ ow, float* __restrict__ w3g) {
    int idx = blockIdx.x * blockDim.x + threadIdx.x;
    if (idx >= 138240) return;
    int ocl = idx & 7;
    int kt  = (idx >> 3) % 9;
    int c   = (idx / 72) % 80;
    int ocg = idx / 5760;
    w3g[idx] = ow[(ocg * 8 + ocl) * 720 + c * 9 + kt];
}

// ---------------- feed selection ----------------
__global__ void k_feed(const float* __restrict__ x, const float* __restrict__ outbuf,
                       float* __restrict__ feed, int t) {
    int i = blockIdx.x * blockDim.x + threadIdx.x;
    if (i >= NB * 3 * SS) return;
    int s = i % SS;
    int ch = (i / SS) % 3;
    int n = i / (3 * SS);
    int y = s / WW, xx = s % WW;
    float v;
    if (t < INPUT_FRAMES || ch == 2) {
        v = x[(((n * TSTEPS + t) * HH + y) * WW + xx) * NCIN + ch];
    } else {
        v = outbuf[(((n * TSTEPS + (t - 1)) * NCOUT + ch) * HH + y) * WW + xx];
    }
    feed[((size_t)(n * 3 + ch) * PR + (y + 1)) * PC + (xx + 1)] = v;
}

// ---------------- generic 3x3 conv, pad=1, fp32, padded inputs (r5-verbatim) ----------------
__global__ __launch_bounds__(192) void k_conv3x3(
    const float* __restrict__ in1, int C1,
    const float* __restrict__ in2, int C2,
    const float* __restrict__ w, const float* __restrict__ b,
    float* __restrict__ out, int OC)
{
    __shared__ __align__(16) float lds_patch[8 * 520];

    const int bx = blockIdx.x;
    const int n = bx / 3, tile = bx % 3;
    const int ocg = blockIdx.y;
    const int C = C1 + C2;
    const int nchunk = (C + 7) / 8;
    const int tid = threadIdx.x;
    const int y0 = tile * 8;

    const float* wg = w + (size_t)ocg * (size_t)(nchunk * 8 * 72);

    const float4* in1_4 = (const float4*)(in1 + (size_t)n * C1 * PHW);
    const float4* in2_4 = (const float4*)(in2 + (size_t)n * C2 * PHW);

    float4 pf[6];
    auto load_chunk = [&](int chunk) {
#pragma unroll
        for (int k = 0; k < 6; ++k) {
            int i = tid + 192 * k;
            if (i < 1040) {
                int c_l = i / 130;
                int rem = i - c_l * 130;
                int c = chunk * 8 + c_l;
                float4 v = make_float4(0.f, 0.f, 0.f, 0.f);
                if (c < C) {
                    v = (c < C1) ? in1_4[(c * PR + y0) * 13 + rem]
                                 : in2_4[((c - C1) * PR + y0) * 13 + rem];
                }
                pf[k] = v;
            }
        }
    };

    const int cg = tid % 24;
    const int ty = tid / 24;
    const int x0 = cg * 2;
    const int y_out = y0 + ty;

    float acc[16];
#pragma unroll
    for (int j = 0; j < 16; ++j) acc[j] = 0.f;

    load_chunk(0);
    for (int chunk = 0; chunk < nchunk; ++chunk) {
        __syncthreads();
#pragma unroll
        for (int k = 0; k < 6; ++k) {
            int i = tid + 192 * k;
            if (i < 1040) ((float4*)lds_patch)[i] = pf[k];
        }
        if (chunk + 1 < nchunk) load_chunk(chunk + 1);
        __syncthreads();

#pragma unroll 2
        for (int icl = 0; icl < 8; ++icl) {
            const int c = chunk * 8 + icl;
            const float* wb_ = wg + c * 72;
            const float* pr = &lds_patch[icl * 520 + ty * PC + x0];
#pragma unroll
            for (int ky = 0; ky < 3; ++ky) {
                const float* r = pr + ky * PC;
                float i0 = r[0], i1 = r[1], i2 = r[2], i3 = r[3];
                const float* wk = wb_ + ky * 24;
#pragma unroll
                for (int kx = 0; kx < 3; ++kx) {
                    float va = (kx == 0) ? i0 : ((kx == 1) ? i1 : i2);
                    float vb = (kx == 0) ? i1 : ((kx == 1) ? i2 : i3);
                    const float4 wa  = *(const float4*)(wk + kx * 8);
                    const float4 wb4 = *(const float4*)(wk + kx * 8 + 4);
                    acc[0]  += va * wa.x;  acc[1]  += va * wa.y;
                    acc[2]  += va * wa.z;  acc[3]  += va * wa.w;
                    acc[4]  += va * wb4.x; acc[5]  += va * wb4.y;
                    acc[6]  += va * wb4.z; acc[7]  += va * wb4.w;
                    acc[8]  += vb * wa.x;  acc[9]  += vb * wa.y;
                    acc[10] += vb * wa.z;  acc[11] += vb * wa.w;
                    acc[12] += vb * wb4.x; acc[13] += vb * wb4.y;
                    acc[14] += vb * wb4.z; acc[15] += vb * wb4.w;
                }
            }
        }
    }

#pragma unroll
    for (int j = 0; j < 8; ++j) {
        int oc = ocg * 8 + j;
        float bv = b[oc];
        float2 o2 = make_float2(acc[j] + bv, acc[8 + j] + bv);
        *(float2*)&out[((n * OC + oc) * HH + y_out) * WW + x0] = o2;
    }
}

// ---------------- ConvLSTM gates (h written padded) ----------------
__global__ void k_lstm_gates(const float* __restrict__ comb, float* __restrict__ c,
                             float* __restrict__ h) {
    int i = blockIdx.x * blockDim.x + threadIdx.x;
    if (i >= NB * HD * SS) return;
    int s = i % SS;
    int ch = (i / SS) % HD;
    int n = i / (HD * SS);
    const float* cb = comb + (size_t)n * 4 * HD * SS;
    float ci = cb[(ch) * SS + s];
    float cf = cb[(ch + HD) * SS + s];
    float co = cb[(ch + 2 * HD) * SS + s];
    float cg = cb[(ch + 3 * HD) * SS + s];
    float ig = sigmoidf_(ci);
    float fg = sigmoidf_(cf);
    float og = sigmoidf_(co);
    float gg = tanhf(cg);
    float cn = fg * c[i] + ig * gg;
    c[i] = cn;
    int y = s / WW, x = s % WW;
    h[((size_t)(n * HD + ch) * PR + (y + 1)) * PC + (x + 1)] = og * tanhf(cn);
}

// ---------------- 1x1 projections, 5 groups x 16 channels ----------------
// grid (72, 5): g=0,1,2 -> q,k,v from h ; g=3,4 -> mk,mv from m
__global__ __launch_bounds__(256) void k_qkv(
    const float* __restrict__ h, const float* __restrict__ m,
    const float* __restrict__ hw, const float* __restrict__ hb,
    const float* __restrict__ mw, const float* __restrict__ mb,
    float* __restrict__ qkv, float* __restrict__ mkv) {
    __shared__ float lw[1024];
    __shared__ float lb[16];
    const int g = blockIdx.y;
    const int tid = threadIdx.x;
    const float* wsrc = (g < 3) ? (hw + g * 1024) : (mw + (g - 3) * 1024);
    const float* bsrc = (g < 3) ? (hb + g * 16) : (mb + (g - 3) * 16);
    for (int i = tid; i < 1024; i += 256) lw[i] = wsrc[i];
    if (tid < 16) lb[tid] = bsrc[tid];
    __syncthreads();

    int idx = blockIdx.x * 256 + tid;
    int s = idx % SS;
    int n = idx / SS;
    int y = s / WW, x = s % WW;

    float reg[HD];
    if (g < 3) {
        const float* src = h + (size_t)n * HD * PHW + (y + 1) * PC + (x + 1);
#pragma unroll
        for (int ic = 0; ic < HD; ++ic) reg[ic] = src[ic * PHW];
    } else {
        const float* src = m + (size_t)n * HD * SS + s;
#pragma unroll
        for (int ic = 0; ic < HD; ++ic) reg[ic] = src[ic * SS];
    }

    float outv[16];
#pragma unroll
    for (int j = 0; j < 16; ++j) {
        const float* wr = &lw[j * HD];
        float a = lb[j];
#pragma unroll
        for (int ic = 0; ic < HD; ++ic) a += reg[ic] * wr[ic];
        outv[j] = a;
    }
    float* dst = (g < 3) ? &qkv[((size_t)n * SS + s) * 48 + g * 16]
                         : &mkv[((size_t)n * SS + s) * 32 + (g - 3) * 16];
#pragma unroll
    for (int j = 0; j < 4; ++j)
        ((float4*)dst)[j] = make_float4(outv[4*j], outv[4*j+1], outv[4*j+2], outv[4*j+3]);
}

#define LOAD16(dst, srcp) do {                       \
    float4 _a = ((const float4*)(srcp))[0];          \
    float4 _b = ((const float4*)(srcp))[1];          \
    float4 _c = ((const float4*)(srcp))[2];          \
    float4 _d = ((const float4*)(srcp))[3];          \
    dst[0]=_a.x; dst[1]=_a.y; dst[2]=_a.z; dst[3]=_a.w;   \
    dst[4]=_b.x; dst[5]=_b.y; dst[6]=_b.z; dst[7]=_b.w;   \
    dst[8]=_c.x; dst[9]=_c.y; dst[10]=_c.z; dst[11]=_c.w; \
    dst[12]=_d.x; dst[13]=_d.y; dst[14]=_d.z; dst[15]=_d.w; } while(0)

// ---------------- dual spatial attention + z 1x1, 2 rows/thread x 16 partials ----------------
// block 256 = 16 row-threads (2 rows each) x 16 t-partials; grid (36, 16)
// KV tile: 144 t x 68 floats (64 data + 4 pad) -> 16 partials tile banks 2-way (free).
// No max-subtraction (|scores| bounded, exp safe in fp32).
// Registers: q 32 + oh/om 64 + l 4 + kk/vv 32 ~= 150 VGPR -> no spill (r6 lesson: 4 rows spilled).
#define TSTRIDE 68
__global__ __launch_bounds__(256) void k_attn(
    const float* __restrict__ qkv, const float* __restrict__ mkv,
    const float* __restrict__ zw, const float* __restrict__ zb,
    float* __restrict__ Z)
{
    __shared__ __align__(16) float smem[144 * TSTRIDE];  // 38.3 KB
    const int n = blockIdx.y;
    const int tid = threadIdx.x;
    const int rowthr = tid >> 4;    // 0..15
    const int part = tid & 15;      // 0..15 (== lane & 15)
    const int s0 = blockIdx.x * 32 + rowthr * 2;

    float q0[16], q1[16];
    LOAD16(q0, &qkv[((size_t)n * SS + s0) * 48]);
    LOAD16(q1, &qkv[((size_t)n * SS + s0 + 1) * 48]);

    float lh0 = 0.f, lh1 = 0.f, lm0 = 0.f, lm1 = 0.f;
    float oh0[16], oh1[16], om0[16], om1[16];
#pragma unroll
    for (int j = 0; j < 16; ++j) { oh0[j] = 0.f; oh1[j] = 0.f; om0[j] = 0.f; om1[j] = 0.f; }

    const float4* qkv4 = (const float4*)qkv + (size_t)n * SS * 12;
    const float4* mkv4 = (const float4*)mkv + (size_t)n * SS * 8;

    for (int tile = 0; tile < 8; ++tile) {
        __syncthreads();
        // stage 144 t: [t][hk16|hv16|mk16|mv16] at stride 68 floats
#pragma unroll
        for (int k = 0; k < 9; ++k) {
            int j = tid + 256 * k;
            int t_loc = j >> 4, f = j & 15;
            int t = tile * 144 + t_loc;
            float4 v;
            if (f < 8) v = qkv4[t * 12 + 4 + f];
            else       v = mkv4[t * 8 + (f - 8)];
            *(float4*)&smem[t_loc * TSTRIDE + f * 4] = v;
        }
        __syncthreads();

        const int t0 = part * 9;
        for (int tl = t0; tl < t0 + 9; ++tl) {
            const float* kvb = &smem[tl * TSTRIDE];
            float kk[16], vv[16];
            // h attention
            LOAD16(kk, kvb);
            float d0 = 0.f, d1 = 0.f;
#pragma unroll
            for (int j = 0; j < 16; ++j) { d0 += q0[j] * kk[j]; d1 += q1[j] * kk[j]; }
            float e0 = __expf(d0 * 0.25f), e1 = __expf(d1 * 0.25f);
            lh0 += e0; lh1 += e1;
            LOAD16(vv, kvb + 16);
#pragma unroll
            for (int j = 0; j < 16; ++j) { oh0[j] += e0 * vv[j]; oh1[j] += e1 * vv[j]; }
            // m attention
            LOAD16(kk, kvb + 32);
            float f0 = 0.f, f1 = 0.f;
#pragma unroll
            for (int j = 0; j < 16; ++j) { f0 += q0[j] * kk[j]; f1 += q1[j] * kk[j]; }
            float g0 = __expf(f0 * 0.25f), g1 = __expf(f1 * 0.25f);
            lm0 += g0; lm1 += g1;
            LOAD16(vv, kvb + 48);
#pragma unroll
            for (int j = 0; j < 16; ++j) { om0[j] += g0 * vv[j]; om1[j] += g1 * vv[j]; }
        }
    }

    // butterfly all-reduce across the 16 partials (lane bits 0..3)
#pragma unroll
    for (int mask = 1; mask <= 8; mask <<= 1) {
        lh0 += __shfl_xor(lh0, mask, 16);
        lh1 += __shfl_xor(lh1, mask, 16);
        lm0 += __shfl_xor(lm0, mask, 16);
        lm1 += __shfl_xor(lm1, mask, 16);
#pragma unroll
        for (int j = 0; j < 16; ++j) {
            oh0[j] += __shfl_xor(oh0[j], mask, 16);
            oh1[j] += __shfl_xor(oh1[j], mask, 16);
            om0[j] += __shfl_xor(om0[j], mask, 16);
            om1[j] += __shfl_xor(om1[j], mask, 16);
        }
    }

    // z projection: this thread's partial id = its z-channel (16 partials = 16 z-ch)
    const int zc = part;
    const float* zr = &zw[zc * 32];
    float zrh[16], zrm[16];
    LOAD16(zrh, zr);
    LOAD16(zrm, zr + 16);
    float zbv = zb[zc];
    float ilh0 = 1.f / lh0, ilh1 = 1.f / lh1;
    float ilm0 = 1.f / lm0, ilm1 = 1.f / lm1;
    float a0 = zbv, a1 = zbv;
#pragma unroll
    for (int j = 0; j < 16; ++j) {
        a0 += zrh[j] * (oh0[j] * ilh0) + zrm[j] * (om0[j] * ilm0);
        a1 += zrh[j] * (oh1[j] * ilh1) + zrm[j] * (om1[j] * ilm1);
    }
    {
        int y0_ = s0 / WW, x0_ = s0 % WW;
        Z[((size_t)(n * DATT + zc) * PR + y0_ + 1) * PC + x0_ + 1] = a0;
        int y1_ = (s0 + 1) / WW, x1_ = (s0 + 1) % WW;
        Z[((size_t)(n * DATT + zc) * PR + y1_ + 1) * PC + x1_ + 1] = a1;
    }
}

// ---------------- SA memory gates (h written padded) ----------------
__global__ void k_sa_gates(const float* __restrict__ iog, float* __restrict__ m,
                           float* __restrict__ h) {
    int i = blockIdx.x * blockDim.x + threadIdx.x;
    if (i >= NB * HD * SS) return;
    int s = i % SS;
    int ch = (i / SS) % HD;
    int n = i / (HD * SS);
    const float* ib = iog + (size_t)n * 3 * HD * SS;
    float si = ib[ch * SS + s];
    float sg = ib[(HD + ch) * SS + s];
    float so = ib[(2 * HD + ch) * SS + s];
    si = sigmoidf_(si);
    sg = tanhf(sg);
    float mn = si * sg + (1.f - si) * m[i];
    m[i] = mn;
    int y = s / WW, x = s % WW;
    h[((size_t)(n * HD + ch) * PR + (y + 1)) * PC + (x + 1)] = sigmoidf_(so) * mn;
}

// ---------------- out 1x1 conv (64 -> 2) ----------------
__global__ void k_out(const float* __restrict__ h, const float* __restrict__ ow,
                      const float* __restrict__ ob, float* __restrict__ outbuf, int t) {
    int idx = blockIdx.x * blockDim.x + threadIdx.x;
    if (idx >= NB * SS) return;
    int s = idx % SS;
    int n = idx / SS;
    int y = s / WW, x = s % WW;
    float reg[HD];
    const float* src = h + (size_t)n * HD * PHW + (y + 1) * PC + (x + 1);
#pragma unroll
    for (int ic = 0; ic < HD; ++ic) reg[ic] = src[ic * PHW];
#pragma unroll
    for (int cc = 0; cc < NCOUT; ++cc) {
        const float* wr = &ow[cc * HD];
        float a = ob[cc];
#pragma unroll
        for (int ic = 0; ic < HD; ++ic) a += reg[ic] * wr[ic];
        outbuf[(((size_t)n * TSTEPS + t) * NCOUT + cc) * SS + s] = a;
    }
}

// ---------------- nino prediction ----------------
__global__ void k_nino(const float* __restrict__ outbuf, float* __restrict__ pred) {
    int tidx = threadIdx.x;
    if (tidx >= 16 * 24) return;
    int j = tidx % 24;
    int n = tidx / 24;
    float acc = 0.f;
    for (int f = j; f < j + 3; ++f) {
        int t = 11 + f;
        const float* p = &outbuf[(((size_t)n * TSTEPS + t) * NCOUT + 0) * SS];
        float sloc = 0.f;
        for (int y = 10; y <= 12; ++y)
            for (int x = 19; x <= 29; ++x)
                sloc += p[y * WW + x];
        acc += sloc * (1.f / 33.f);
    }
    pred[n * 24 + j] = acc * (1.f / 3.f);
}

extern "C" void kernel_launch(void* const* d_in, const int* in_sizes, int n_in,
                              void* d_out, int out_size, void* d_ws, size_t ws_size,
                              hipStream_t stream) {
    const float* x      = (const float*)d_in[0];
    const float* conv_w = (const float*)d_in[1];
    const float* conv_b = (const float*)d_in[2];
    const float* h_w    = (const float*)d_in[3];
    const float* h_b    = (const float*)d_in[4];
    const float* m_w    = (const float*)d_in[5];
    const float* m_b    = (const float*)d_in[6];
    const float* z_w    = (const float*)d_in[7];
    const float* z_b    = (const float*)d_in[8];
    const float* o_w    = (const float*)d_in[9];
    const float* o_b    = (const float*)d_in[10];
    const float* out_w  = (const float*)d_in[11];
    const float* out_b  = (const float*)d_in[12];

    float* ws   = (float*)d_ws;
    float* h    = ws + OFF_H;
    float* c    = ws + OFF_C;
    float* m    = ws + OFF_M;
    float* feed = ws + OFF_FEED;
    float* comb = ws + OFF_COMB;
    float* qkv  = ws + OFF_QKV;
    float* mkv  = ws + OFF_MKV;
    float* Zb   = ws + OFF_Z;
    float* iog  = ws + OFF_IOG;
    float* w2g  = ws + OFF_W2G;
    float* w3g  = ws + OFF_W3G;
    float* outp = (float*)d_out;

    k_zero<<<4058, 256, 0, stream>>>(ws, 1038688);
    k_prep_w2g<<<648, 256, 0, stream>>>(conv_w, w2g);
    k_prep_w3g<<<540, 256, 0, stream>>>(o_w, w3g);

    for (int t = 0; t < TSTEPS; ++t) {
        k_feed<<<216, 256, 0, stream>>>(x, outp, feed, t);
        k_conv3x3<<<dim3(48, 32), 192, 0, stream>>>(feed, 3, h, HD, w2g, conv_b,
                                                    comb, 4 * HD);
        k_lstm_gates<<<4608, 256, 0, stream>>>(comb, c, h);
        k_qkv<<<dim3(72, 5), 256, 0, stream>>>(h, m, h_w, h_b, m_w, m_b, qkv, mkv);
        k_attn<<<dim3(36, 16), 256, 0, stream>>>(qkv, mkv, z_w, z_b, Zb);
        k_conv3x3<<<dim3(48, 24), 192, 0, stream>>>(Zb, DATT, h, HD, w3g, o_b,
                                                    iog, 3 * HD);
        k_sa_gates<<<4608, 256, 0, stream>>>(iog, m, h);
        k_out<<<72, 256, 0, stream>>>(h, out_w, out_b, outp, t);
    }
    k_nino<<<1, 384, 0, stream>>>(outp, outp + (size_t)NB * TSTEPS * NCOUT * SS);
}

// Round 8
// 11718.527 us; speedup vs baseline: 1.8476x; 1.4156x over previous
//
#include <hip/hip_runtime.h>
#include <math.h>

#define HD 64
#define DATT 16
#define NCIN 3
#define NCOUT 2
#define HH 24
#define WW 48
#define SS (HH*WW)          // 1152
#define NB 16
#define TSTEPS 37
#define INPUT_FRAMES 12

#define PR 26
#define PC 52
#define PHW (PR*PC)         // 1352

// ---------------- workspace layout (floats) ----------------
#define OFF_H     0                      // 16*64*1352 = 1384448 (padded)
#define OFF_C     1384448                // 16*64*1152 (unpadded)
#define OFF_M     2564096                // 16*64*1152 (unpadded)
#define OFF_FEED  3743744                // 16*3*1352 (padded)
#define OFF_Z     3808640                // 16*16*1352 (padded)
#define ZERO_END  4154752                // everything above zeroed each launch
#define OFF_COMB  4154752                // 16*256*1152 = 4718592
#define OFF_QKV   4154752                // aliases comb (dead after lstm gates)
#define OFF_MKV   5039488                // qkv + 884736
#define OFF_IOG   8873344                // comb + 4718592
#define OFF_W2G   12412288               // 32*72*9*8 = 165888
#define OFF_W3G   12578176               // 24*80*9*8 = 138240
// end = 12716416 floats = 50.9 MB

__device__ __forceinline__ float sigmoidf_(float x) {
    return 1.0f / (1.0f + __expf(-x));
}

__global__ void k_zero(float* __restrict__ p, int n4) {
    int i = blockIdx.x * blockDim.x + threadIdx.x;
    if (i < n4) ((float4*)p)[i] = make_float4(0.f, 0.f, 0.f, 0.f);
}

// ---------------- weight reorder: conv_w -> w2g [ocg(32)][c(72)][kt(9)][ocl(8)] ----------------
__global__ void k_prep_w2g(const float* __restrict__ cw, float* __restrict__ w2g) {
    int idx = blockIdx.x * blockDim.x + threadIdx.x;
    if (idx >= 165888) return;
    int ocl = idx & 7;
    int kt  = (idx >> 3) % 9;
    int c   = (idx / 72) % 72;
    int ocg = idx / 5184;
    w2g[idx] = (c < 67) ? cw[(ocg * 8 + ocl) * 603 + c * 9 + kt] : 0.f;
}

// ---------------- weight reorder: o_w -> w3g [ocg(24)][c(80)][kt(9)][ocl(8)] ----------------
__global__ void k_prep_w3g(const float* __restrict__ ow, float* __restrict__ w3g) {
    int idx = blockIdx.x * blockDim.x + threadIdx.x;
    if (idx >= 138240) return;
    int ocl = idx & 7;
    int kt  = (idx >> 3) % 9;
    int c   = (idx / 72) % 80;
    int ocg = idx / 5760;
    w3g[idx] = ow[(ocg * 8 + ocl) * 720 + c * 9 + kt];
}

// ---------------- feed selection ----------------
__global__ void k_feed(const float* __restrict__ x, const float* __restrict__ outbuf,
                       float* __restrict__ feed, int t) {
    int i = blockIdx.x * blockDim.x + threadIdx.x;
    if (i >= NB * 3 * SS) return;
    int s = i % SS;
    int ch = (i / SS) % 3;
    int n = i / (3 * SS);
    int y = s / WW, xx = s % WW;
    float v;
    if (t < INPUT_FRAMES || ch == 2) {
        v = x[(((n * TSTEPS + t) * HH + y) * WW + xx) * NCIN + ch];
    } else {
        v = outbuf[(((n * TSTEPS + (t - 1)) * NCOUT + ch) * HH + y) * WW + xx];
    }
    feed[((size_t)(n * 3 + ch) * PR + (y + 1)) * PC + (xx + 1)] = v;
}

// ---------------- generic 3x3 conv, pad=1, fp32, padded inputs ----------------
// Each block computes TWO oc-groups (16 oc) per patch staging (amortize staging 2x).
// in1/in2 PADDED [C][26][52]; out unpadded NCHW; w pre-reordered [ocg][Cpad][9][8].
// grid: (48, OC/16); block 192 = 24 col-groups (2 px) x 8 rows
__global__ __launch_bounds__(192) void k_conv3x3(
    const float* __restrict__ in1, int C1,
    const float* __restrict__ in2, int C2,
    const float* __restrict__ w, const float* __restrict__ b,
    float* __restrict__ out, int OC)
{
    __shared__ __align__(16) float lds_patch[8 * 520];

    const int bx = blockIdx.x;
    const int n = bx / 3, tile = bx % 3;
    const int ocp = blockIdx.y;                 // oc-pair index
    const int C = C1 + C2;
    const int nchunk = (C + 7) / 8;
    const int tid = threadIdx.x;
    const int y0 = tile * 8;

    const int wgsz = nchunk * 8 * 72;
    const float* wg0 = w + (size_t)(ocp * 2) * wgsz;
    const float* wg1 = wg0 + wgsz;

    const float4* in1_4 = (const float4*)(in1 + (size_t)n * C1 * PHW);
    const float4* in2_4 = (const float4*)(in2 + (size_t)n * C2 * PHW);

    float4 pf[6];
    auto load_chunk = [&](int chunk) {
#pragma unroll
        for (int k = 0; k < 6; ++k) {
            int i = tid + 192 * k;
            if (i < 1040) {
                int c_l = i / 130;
                int rem = i - c_l * 130;
                int c = chunk * 8 + c_l;
                float4 v = make_float4(0.f, 0.f, 0.f, 0.f);
                if (c < C) {
                    v = (c < C1) ? in1_4[(c * PR + y0) * 13 + rem]
                                 : in2_4[((c - C1) * PR + y0) * 13 + rem];
                }
                pf[k] = v;
            }
        }
    };

    const int cg = tid % 24;
    const int ty = tid / 24;
    const int x0 = cg * 2;
    const int y_out = y0 + ty;

    float acc[32];
#pragma unroll
    for (int j = 0; j < 32; ++j) acc[j] = 0.f;

    load_chunk(0);
    for (int chunk = 0; chunk < nchunk; ++chunk) {
        __syncthreads();
#pragma unroll
        for (int k = 0; k < 6; ++k) {
            int i = tid + 192 * k;
            if (i < 1040) ((float4*)lds_patch)[i] = pf[k];
        }
        if (chunk + 1 < nchunk) load_chunk(chunk + 1);
        __syncthreads();

        for (int icl = 0; icl < 8; ++icl) {
            const int c = chunk * 8 + icl;
            const float* wb0 = wg0 + c * 72;    // block-uniform
            const float* wb1 = wg1 + c * 72;
            const float* pr = &lds_patch[icl * 520 + ty * PC + x0];
#pragma unroll
            for (int ky = 0; ky < 3; ++ky) {
                const float* r = pr + ky * PC;
                float i0 = r[0], i1 = r[1], i2 = r[2], i3 = r[3];
                const float* wk0 = wb0 + ky * 24;
                const float* wk1 = wb1 + ky * 24;
#pragma unroll
                for (int kx = 0; kx < 3; ++kx) {
                    float va = (kx == 0) ? i0 : ((kx == 1) ? i1 : i2);
                    float vb = (kx == 0) ? i1 : ((kx == 1) ? i2 : i3);
                    const float4 wa0  = *(const float4*)(wk0 + kx * 8);
                    const float4 wb40 = *(const float4*)(wk0 + kx * 8 + 4);
                    const float4 wa1  = *(const float4*)(wk1 + kx * 8);
                    const float4 wb41 = *(const float4*)(wk1 + kx * 8 + 4);
                    acc[0]  += va * wa0.x;  acc[1]  += va * wa0.y;
                    acc[2]  += va * wa0.z;  acc[3]  += va * wa0.w;
                    acc[4]  += va * wb40.x; acc[5]  += va * wb40.y;
                    acc[6]  += va * wb40.z; acc[7]  += va * wb40.w;
                    acc[8]  += vb * wa0.x;  acc[9]  += vb * wa0.y;
                    acc[10] += vb * wa0.z;  acc[11] += vb * wa0.w;
                    acc[12] += vb * wb40.x; acc[13] += vb * wb40.y;
                    acc[14] += vb * wb40.z; acc[15] += vb * wb40.w;
                    acc[16] += va * wa1.x;  acc[17] += va * wa1.y;
                    acc[18] += va * wa1.z;  acc[19] += va * wa1.w;
                    acc[20] += va * wb41.x; acc[21] += va * wb41.y;
                    acc[22] += va * wb41.z; acc[23] += va * wb41.w;
                    acc[24] += vb * wa1.x;  acc[25] += vb * wa1.y;
                    acc[26] += vb * wa1.z;  acc[27] += vb * wa1.w;
                    acc[28] += vb * wb41.x; acc[29] += vb * wb41.y;
                    acc[30] += vb * wb41.z; acc[31] += vb * wb41.w;
                }
            }
        }
    }

#pragma unroll
    for (int j = 0; j < 8; ++j) {
        int oc0 = ocp * 16 + j;
        int oc1 = ocp * 16 + 8 + j;
        float bv0 = b[oc0];
        float bv1 = b[oc1];
        float2 o0 = make_float2(acc[j] + bv0, acc[8 + j] + bv0);
        float2 o1 = make_float2(acc[16 + j] + bv1, acc[24 + j] + bv1);
        *(float2*)&out[((n * OC + oc0) * HH + y_out) * WW + x0] = o0;
        *(float2*)&out[((n * OC + oc1) * HH + y_out) * WW + x0] = o1;
    }
}

// ---------------- ConvLSTM gates (h written padded) ----------------
__global__ void k_lstm_gates(const float* __restrict__ comb, float* __restrict__ c,
                             float* __restrict__ h) {
    int i = blockIdx.x * blockDim.x + threadIdx.x;
    if (i >= NB * HD * SS) return;
    int s = i % SS;
    int ch = (i / SS) % HD;
    int n = i / (HD * SS);
    const float* cb = comb + (size_t)n * 4 * HD * SS;
    float ci = cb[(ch) * SS + s];
    float cf = cb[(ch + HD) * SS + s];
    float co = cb[(ch + 2 * HD) * SS + s];
    float cg = cb[(ch + 3 * HD) * SS + s];
    float ig = sigmoidf_(ci);
    float fg = sigmoidf_(cf);
    float og = sigmoidf_(co);
    float gg = tanhf(cg);
    float cn = fg * c[i] + ig * gg;
    c[i] = cn;
    int y = s / WW, x = s % WW;
    h[((size_t)(n * HD + ch) * PR + (y + 1)) * PC + (x + 1)] = og * tanhf(cn);
}

// ---------------- 1x1 q/k/v + mk/mv projections (r5-verbatim, 10 groups x 8ch) ----------------
__global__ __launch_bounds__(256) void k_qkv(
    const float* __restrict__ h, const float* __restrict__ m,
    const float* __restrict__ hw, const float* __restrict__ hb,
    const float* __restrict__ mw, const float* __restrict__ mb,
    float* __restrict__ qkv, float* __restrict__ mkv) {
    __shared__ float lw[512];
    __shared__ float lb[8];
    const int g = blockIdx.y;
    const int tid = threadIdx.x;
    const float* wsrc = (g < 6) ? (hw + g * 512) : (mw + (g - 6) * 512);
    const float* bsrc = (g < 6) ? (hb + g * 8) : (mb + (g - 6) * 8);
    for (int i = tid; i < 512; i += 256) lw[i] = wsrc[i];
    if (tid < 8) lb[tid] = bsrc[tid];
    __syncthreads();

    int idx = blockIdx.x * 256 + tid;
    int s = idx % SS;
    int n = idx / SS;
    int y = s / WW, x = s % WW;

    float reg[HD];
    if (g < 6) {
        const float* src = h + (size_t)n * HD * PHW + (y + 1) * PC + (x + 1);
#pragma unroll
        for (int ic = 0; ic < HD; ++ic) reg[ic] = src[ic * PHW];
    } else {
        const float* src = m + (size_t)n * HD * SS + s;
#pragma unroll
        for (int ic = 0; ic < HD; ++ic) reg[ic] = src[ic * SS];
    }

    float* dst = (g < 6) ? &qkv[((size_t)n * SS + s) * 48 + g * 8]
                         : &mkv[((size_t)n * SS + s) * 32 + (g - 6) * 8];
#pragma unroll
    for (int j = 0; j < 8; ++j) {
        const float* wr = &lw[j * HD];
        float a = lb[j];
#pragma unroll
        for (int ic = 0; ic < HD; ++ic) a += reg[ic] * wr[ic];
        dst[j] = a;
    }
}

#define LOAD16(dst, srcp) do {                       \
    float4 _a = ((const float4*)(srcp))[0];          \
    float4 _b = ((const float4*)(srcp))[1];          \
    float4 _c = ((const float4*)(srcp))[2];          \
    float4 _d = ((const float4*)(srcp))[3];          \
    dst[0]=_a.x; dst[1]=_a.y; dst[2]=_a.z; dst[3]=_a.w;   \
    dst[4]=_b.x; dst[5]=_b.y; dst[6]=_b.z; dst[7]=_b.w;   \
    dst[8]=_c.x; dst[9]=_c.y; dst[10]=_c.z; dst[11]=_c.w; \
    dst[12]=_d.x; dst[13]=_d.y; dst[14]=_d.z; dst[15]=_d.w; } while(0)

// ---------------- dual spatial attention + z 1x1 (r7-verbatim) ----------------
// block 256 = 16 row-threads (2 rows each) x 16 t-partials; grid (36, 16)
#define TSTRIDE 68
__global__ __launch_bounds__(256) void k_attn(
    const float* __restrict__ qkv, const float* __restrict__ mkv,
    const float* __restrict__ zw, const float* __restrict__ zb,
    float* __restrict__ Z)
{
    __shared__ __align__(16) float smem[144 * TSTRIDE];  // 38.3 KB
    const int n = blockIdx.y;
    const int tid = threadIdx.x;
    const int rowthr = tid >> 4;    // 0..15
    const int part = tid & 15;      // 0..15 (== lane & 15)
    const int s0 = blockIdx.x * 32 + rowthr * 2;

    float q0[16], q1[16];
    LOAD16(q0, &qkv[((size_t)n * SS + s0) * 48]);
    LOAD16(q1, &qkv[((size_t)n * SS + s0 + 1) * 48]);

    float lh0 = 0.f, lh1 = 0.f, lm0 = 0.f, lm1 = 0.f;
    float oh0[16], oh1[16], om0[16], om1[16];
#pragma unroll
    for (int j = 0; j < 16; ++j) { oh0[j] = 0.f; oh1[j] = 0.f; om0[j] = 0.f; om1[j] = 0.f; }

    const float4* qkv4 = (const float4*)qkv + (size_t)n * SS * 12;
    const float4* mkv4 = (const float4*)mkv + (size_t)n * SS * 8;

    for (int tile = 0; tile < 8; ++tile) {
        __syncthreads();
#pragma unroll
        for (int k = 0; k < 9; ++k) {
            int j = tid + 256 * k;
            int t_loc = j >> 4, f = j & 15;
            int t = tile * 144 + t_loc;
            float4 v;
            if (f < 8) v = qkv4[t * 12 + 4 + f];
            else       v = mkv4[t * 8 + (f - 8)];
            *(float4*)&smem[t_loc * TSTRIDE + f * 4] = v;
        }
        __syncthreads();

        const int t0 = part * 9;
        for (int tl = t0; tl < t0 + 9; ++tl) {
            const float* kvb = &smem[tl * TSTRIDE];
            float kk[16], vv[16];
            LOAD16(kk, kvb);
            float d0 = 0.f, d1 = 0.f;
#pragma unroll
            for (int j = 0; j < 16; ++j) { d0 += q0[j] * kk[j]; d1 += q1[j] * kk[j]; }
            float e0 = __expf(d0 * 0.25f), e1 = __expf(d1 * 0.25f);
            lh0 += e0; lh1 += e1;
            LOAD16(vv, kvb + 16);
#pragma unroll
            for (int j = 0; j < 16; ++j) { oh0[j] += e0 * vv[j]; oh1[j] += e1 * vv[j]; }
            LOAD16(kk, kvb + 32);
            float f0 = 0.f, f1 = 0.f;
#pragma unroll
            for (int j = 0; j < 16; ++j) { f0 += q0[j] * kk[j]; f1 += q1[j] * kk[j]; }
            float g0 = __expf(f0 * 0.25f), g1 = __expf(f1 * 0.25f);
            lm0 += g0; lm1 += g1;
            LOAD16(vv, kvb + 48);
#pragma unroll
            for (int j = 0; j < 16; ++j) { om0[j] += g0 * vv[j]; om1[j] += g1 * vv[j]; }
        }
    }

#pragma unroll
    for (int mask = 1; mask <= 8; mask <<= 1) {
        lh0 += __shfl_xor(lh0, mask, 16);
        lh1 += __shfl_xor(lh1, mask, 16);
        lm0 += __shfl_xor(lm0, mask, 16);
        lm1 += __shfl_xor(lm1, mask, 16);
#pragma unroll
        for (int j = 0; j < 16; ++j) {
            oh0[j] += __shfl_xor(oh0[j], mask, 16);
            oh1[j] += __shfl_xor(oh1[j], mask, 16);
            om0[j] += __shfl_xor(om0[j], mask, 16);
            om1[j] += __shfl_xor(om1[j], mask, 16);
        }
    }

    const int zc = part;
    const float* zr = &zw[zc * 32];
    float zrh[16], zrm[16];
    LOAD16(zrh, zr);
    LOAD16(zrm, zr + 16);
    float zbv = zb[zc];
    float ilh0 = 1.f / lh0, ilh1 = 1.f / lh1;
    float ilm0 = 1.f / lm0, ilm1 = 1.f / lm1;
    float a0 = zbv, a1 = zbv;
#pragma unroll
    for (int j = 0; j < 16; ++j) {
        a0 += zrh[j] * (oh0[j] * ilh0) + zrm[j] * (om0[j] * ilm0);
        a1 += zrh[j] * (oh1[j] * ilh1) + zrm[j] * (om1[j] * ilm1);
    }
    {
        int y0_ = s0 / WW, x0_ = s0 % WW;
        Z[((size_t)(n * DATT + zc) * PR + y0_ + 1) * PC + x0_ + 1] = a0;
        int y1_ = (s0 + 1) / WW, x1_ = (s0 + 1) % WW;
        Z[((size_t)(n * DATT + zc) * PR + y1_ + 1) * PC + x1_ + 1] = a1;
    }
}

// ---------------- SA memory gates (h written padded) ----------------
__global__ void k_sa_gates(const float* __restrict__ iog, float* __restrict__ m,
                           float* __restrict__ h) {
    int i = blockIdx.x * blockDim.x + threadIdx.x;
    if (i >= NB * HD * SS) return;
    int s = i % SS;
    int ch = (i / SS) % HD;
    int n = i / (HD * SS);
    const float* ib = iog + (size_t)n * 3 * HD * SS;
    float si = ib[ch * SS + s];
    float sg = ib[(HD + ch) * SS + s];
    float so = ib[(2 * HD + ch) * SS + s];
    si = sigmoidf_(si);
    sg = tanhf(sg);
    float mn = si * sg + (1.f - si) * m[i];
    m[i] = mn;
    int y = s / WW, x = s % WW;
    h[((size_t)(n * HD + ch) * PR + (y + 1)) * PC + (x + 1)] = sigmoidf_(so) * mn;
}

// ---------------- out 1x1 conv (64 -> 2) ----------------
__global__ void k_out(const float* __restrict__ h, const float* __restrict__ ow,
                      const float* __restrict__ ob, float* __restrict__ outbuf, int t) {
    int idx = blockIdx.x * blockDim.x + threadIdx.x;
    if (idx >= NB * SS) return;
    int s = idx % SS;
    int n = idx / SS;
    int y = s / WW, x = s % WW;
    float reg[HD];
    const float* src = h + (size_t)n * HD * PHW + (y + 1) * PC + (x + 1);
#pragma unroll
    for (int ic = 0; ic < HD; ++ic) reg[ic] = src[ic * PHW];
#pragma unroll
    for (int cc = 0; cc < NCOUT; ++cc) {
        const float* wr = &ow[cc * HD];
        float a = ob[cc];
#pragma unroll
        for (int ic = 0; ic < HD; ++ic) a += reg[ic] * wr[ic];
        outbuf[(((size_t)n * TSTEPS + t) * NCOUT + cc) * SS + s] = a;
    }
}

// ---------------- nino prediction ----------------
__global__ void k_nino(const float* __restrict__ outbuf, float* __restrict__ pred) {
    int tidx = threadIdx.x;
    if (tidx >= 16 * 24) return;
    int j = tidx % 24;
    int n = tidx / 24;
    float acc = 0.f;
    for (int f = j; f < j + 3; ++f) {
        int t = 11 + f;
        const float* p = &outbuf[(((size_t)n * TSTEPS + t) * NCOUT + 0) * SS];
        float sloc = 0.f;
        for (int y = 10; y <= 12; ++y)
            for (int x = 19; x <= 29; ++x)
                sloc += p[y * WW + x];
        acc += sloc * (1.f / 33.f);
    }
    pred[n * 24 + j] = acc * (1.f / 3.f);
}

extern "C" void kernel_launch(void* const* d_in, const int* in_sizes, int n_in,
                              void* d_out, int out_size, void* d_ws, size_t ws_size,
                              hipStream_t stream) {
    const float* x      = (const float*)d_in[0];
    const float* conv_w = (const float*)d_in[1];
    const float* conv_b = (const float*)d_in[2];
    const float* h_w    = (const float*)d_in[3];
    const float* h_b    = (const float*)d_in[4];
    const float* m_w    = (const float*)d_in[5];
    const float* m_b    = (const float*)d_in[6];
    const float* z_w    = (const float*)d_in[7];
    const float* z_b    = (const float*)d_in[8];
    const float* o_w    = (const float*)d_in[9];
    const float* o_b    = (const float*)d_in[10];
    const float* out_w  = (const float*)d_in[11];
    const float* out_b  = (const float*)d_in[12];

    float* ws   = (float*)d_ws;
    float* h    = ws + OFF_H;
    float* c    = ws + OFF_C;
    float* m    = ws + OFF_M;
    float* feed = ws + OFF_FEED;
    float* comb = ws + OFF_COMB;
    float* qkv  = ws + OFF_QKV;
    float* mkv  = ws + OFF_MKV;
    float* Zb   = ws + OFF_Z;
    float* iog  = ws + OFF_IOG;
    float* w2g  = ws + OFF_W2G;
    float* w3g  = ws + OFF_W3G;
    float* outp = (float*)d_out;

    k_zero<<<4058, 256, 0, stream>>>(ws, 1038688);
    k_prep_w2g<<<648, 256, 0, stream>>>(conv_w, w2g);
    k_prep_w3g<<<540, 256, 0, stream>>>(o_w, w3g);

    for (int t = 0; t < TSTEPS; ++t) {
        k_feed<<<216, 256, 0, stream>>>(x, outp, feed, t);
        k_conv3x3<<<dim3(48, 16), 192, 0, stream>>>(feed, 3, h, HD, w2g, conv_b,
                                                    comb, 4 * HD);
        k_lstm_gates<<<4608, 256, 0, stream>>>(comb, c, h);
        k_qkv<<<dim3(72, 10), 256, 0, stream>>>(h, m, h_w, h_b, m_w, m_b, qkv, mkv);
        k_attn<<<dim3(36, 16), 256, 0, stream>>>(qkv, mkv, z_w, z_b, Zb);
        k_conv3x3<<<dim3(48, 12), 192, 0, stream>>>(Zb, DATT, h, HD, w3g, o_b,
                                                    iog, 3 * HD);
        k_sa_gates<<<4608, 256, 0, stream>>>(iog, m, h);
        k_out<<<72, 256, 0, stream>>>(h, out_w, out_b, outp, t);
    }
    k_nino<<<1, 384, 0, stream>>>(outp, outp + (size_t)NB * TSTEPS * NCOUT * SS);
}